// Round 1
// baseline (100.435 us; speedup 1.0000x reference)
//
#include <hip/hip_runtime.h>
#include <math.h>

#define NUM_CAM   12   // B*N
#define CAM_PER_B 6
#define IMG_H     128
#define IMG_W     352
#define CH        32
#define BEV       200  // BEV_H == BEV_W
#define PIX_PER_B (BEV * BEV)        // 40000
#define PIX_PER_BLOCK 32
#define BLOCKS_PER_B (PIX_PER_B / PIX_PER_BLOCK)  // 1250

// One block = 32 consecutive BEV pixels (all within one batch b).
// 8 threads per pixel, each handling 4 channels (float4).
__global__ __launch_bounds__(256) void ipm_kernel(
    const float* __restrict__ imgs,   // (12, 128, 352, 32)
    const float* __restrict__ Ks,     // (12, 4, 4)
    const float* __restrict__ RTs,    // (12, 4, 4)
    float* __restrict__ out)          // (2, 200, 200, 32)
{
    __shared__ float sP[CAM_PER_B][9];  // rows 0..2 of P, cols {0,1,3}

    const int tid = threadIdx.x;
    const int b = blockIdx.x / BLOCKS_PER_B;

    // Compute the 6 projection matrices' needed coefficients for this batch.
    // P = K @ RT (f32, k-ordered accumulation like the reference matmul).
    if (tid < CAM_PER_B * 9) {
        const int cl = tid / 9;         // camera within batch
        const int k  = tid % 9;
        const int r  = k / 3;           // P row 0..2
        const int cc = k % 3;           // 0,1,2 -> cols 0,1,3
        const int col = (cc == 2) ? 3 : cc;
        const float* K  = Ks  + (b * CAM_PER_B + cl) * 16;
        const float* RT = RTs + (b * CAM_PER_B + cl) * 16;
        float acc = 0.0f;
        #pragma unroll
        for (int kk = 0; kk < 4; ++kk)
            acc += K[r * 4 + kk] * RT[kk * 4 + col];
        sP[cl][k] = acc;
    }
    __syncthreads();

    const int px_in_block = tid >> 3;          // 0..31
    const int c4 = (tid & 7) * 4;              // channel offset
    const int pix_id = blockIdx.x * PIX_PER_BLOCK + px_in_block;
    const int rem = pix_id - b * PIX_PER_B;
    const int gy = rem / BEV;
    const int gx = rem - gy * BEV;

    // linspace(-50, 50, 200) computed in f64 then cast to f32 (matches numpy)
    const double step = 100.0 / 199.0;
    const float xf = (float)(-50.0 + (double)gx * step);
    const float yf = (float)(-50.0 + (double)gy * step);

    float4 best = make_float4(-INFINITY, -INFINITY, -INFINITY, -INFINITY);

    #pragma unroll
    for (int n = 0; n < CAM_PER_B; ++n) {
        const float p00 = sP[n][0], p01 = sP[n][1], p03 = sP[n][2];
        const float p10 = sP[n][3], p11 = sP[n][4], p13 = sP[n][5];
        const float p20 = sP[n][6], p21 = sP[n][7], p23 = sP[n][8];

        // pc = P @ [yf, xf, 0, 1]
        const float den = (p20 * yf + p21 * xf + p23) + 1e-7f;
        const float px  = (p00 * yf + p01 * xf + p03) / den;
        const float py  = (p10 * yf + p11 * xf + p13) / den;

        const float x0f = floorf(px);
        const float y0f = floorf(py);

        float4 val = make_float4(0.0f, 0.0f, 0.0f, 0.0f);
        // Out-of-range => reference's clipped weights cancel to exactly 0.0
        if (x0f >= 0.0f && x0f <= (float)(IMG_W - 2) &&
            y0f >= 0.0f && y0f <= (float)(IMG_H - 2)) {
            // Reference weight formulas (x1 = x0+1, unclipped since in range)
            const float wx1 = px - x0f;
            const float wx0 = (x0f + 1.0f) - px;
            const float wy1 = py - y0f;
            const float wy0 = (y0f + 1.0f) - py;

            const int xi = (int)x0f;
            const int yi = (int)y0f;
            const int cam = b * CAM_PER_B + n;
            const float* base =
                imgs + (((size_t)cam * IMG_H + yi) * IMG_W + xi) * CH + c4;

            const float4 a00 = *(const float4*)(base);
            const float4 a10 = *(const float4*)(base + CH);
            const float4 a01 = *(const float4*)(base + (size_t)IMG_W * CH);
            const float4 a11 = *(const float4*)(base + (size_t)IMG_W * CH + CH);

            const float w00 = wx0 * wy0;
            const float w01 = wx0 * wy1;
            const float w10 = wx1 * wy0;
            const float w11 = wx1 * wy1;

            // Same summation order as reference:
            // ((t00 + t01) + t10) + t11
            val.x = ((w00 * a00.x + w01 * a01.x) + w10 * a10.x) + w11 * a11.x;
            val.y = ((w00 * a00.y + w01 * a01.y) + w10 * a10.y) + w11 * a11.y;
            val.z = ((w00 * a00.z + w01 * a01.z) + w10 * a10.z) + w11 * a11.z;
            val.w = ((w00 * a00.w + w01 * a01.w) + w10 * a10.w) + w11 * a11.w;
        }

        best.x = fmaxf(best.x, val.x);
        best.y = fmaxf(best.y, val.y);
        best.z = fmaxf(best.z, val.z);
        best.w = fmaxf(best.w, val.w);
    }

    *(float4*)(out + (size_t)pix_id * CH + c4) = best;
}

extern "C" void kernel_launch(void* const* d_in, const int* in_sizes, int n_in,
                              void* d_out, int out_size, void* d_ws, size_t ws_size,
                              hipStream_t stream) {
    const float* images = (const float*)d_in[0];  // (2,6,128,352,32) f32
    const float* Ks     = (const float*)d_in[1];  // (12,4,4) f32
    const float* RTs    = (const float*)d_in[2];  // (12,4,4) f32
    float* out          = (float*)d_out;          // (2,200,200,32) f32

    const int total_blocks = 2 * BLOCKS_PER_B;    // 2500
    ipm_kernel<<<total_blocks, 256, 0, stream>>>(images, Ks, RTs, out);
}